// Round 2
// baseline (419.402 us; speedup 1.0000x reference)
//
#include <hip/hip_runtime.h>
#include <hip/hip_bf16.h>

#define DD 768
#define HH 3072
#define BB 64
#define TT 262   // NCLS + P tokens per batch

typedef __bf16 bf16x8 __attribute__((ext_vector_type(8)));
typedef float f32x4 __attribute__((ext_vector_type(4)));
typedef unsigned short u16;
typedef unsigned int u32;

__device__ __constant__ int A_FIRST[12]  = {0,3, 0,4, 1,3, 1,4, 2,3, 2,4};
__device__ __constant__ int A_SECOND[12] = {3,0, 4,0, 3,1, 4,1, 3,2, 4,2};

// tanh-form gelu: max |dev| from exact erf-gelu ~0.003 abs; output tol 0.039 -> safe
__device__ __forceinline__ float gelu_f(float x) {
  float n2t = x * fmaf(x * x, -0.0713548163f, -1.5957691216f);
  return x * __builtin_amdgcn_rcpf(1.0f + __expf(n2t));
}

__device__ __forceinline__ u16 f2bf(float x) {
  u32 u = __builtin_bit_cast(u32, x);
  return (u16)((u + 0x7fffu + ((u >> 16) & 1u)) >> 16);  // RNE
}

__device__ __forceinline__ void load_lds16(const void* g, void* l) {
  __builtin_amdgcn_global_load_lds(
      (const __attribute__((address_space(1))) void*)g,
      (__attribute__((address_space(3))) void*)l,
      16, 0, 0);
}

// counted waits / raw barrier (T4): raw s_barrier does NOT drain vmcnt.
// "memory" clobber pins DMA issues and LDS reads relative to the wait.
#define VMCNT(n) asm volatile("s_waitcnt vmcnt(" #n ")" ::: "memory")
#define BAR() __builtin_amdgcn_s_barrier()

// =================== fused preprocessing: cast_x | transpose x2 | gate ===================
__global__ __launch_bounds__(256)
void preproc(const float* __restrict__ x,
             const float* __restrict__ W1, const float* __restrict__ A1W,
             const float* __restrict__ W2, const float* __restrict__ A2W,
             const float* __restrict__ GW,
             __hip_bfloat16* __restrict__ xb,
             __hip_bfloat16* __restrict__ W1t, __hip_bfloat16* __restrict__ A1t,
             __hip_bfloat16* __restrict__ W2t, __hip_bfloat16* __restrict__ A2t,
             int* __restrict__ sel) {
  __shared__ __hip_bfloat16 tile[32][33];
  const int bx = blockIdx.x;
  const int tid = threadIdx.x;
  if (bx < 12576) {
    int i = bx * 256 + tid;  // 12576*256 == 3219456 exactly
    float4 v = ((const float4*)x)[i];
    union { u16 s[4]; uint2 d; } pk;
    pk.s[0] = f2bf(v.x); pk.s[1] = f2bf(v.y); pk.s[2] = f2bf(v.z); pk.s[3] = f2bf(v.w);
    *(uint2*)((u16*)xb + (size_t)i * 4) = pk.d;
  } else if (bx < 40224) {
    int R, C;
    const float* ip;
    __hip_bfloat16* op;
    int t;
    if (bx < 26400) {
      t = bx - 12576; R = DD; C = HH;
      int z = t / 2304; t %= 2304;
      ip = z ? (A1W + (size_t)(z - 1) * DD * HH) : W1;
      op = z ? (A1t + (size_t)(z - 1) * DD * HH) : W1t;
    } else {
      t = bx - 26400; R = HH; C = DD;
      int z = t / 2304; t %= 2304;
      ip = z ? (A2W + (size_t)(z - 1) * DD * HH) : W2;
      op = z ? (A2t + (size_t)(z - 1) * DD * HH) : W2t;
    }
    int ctiles = C >> 5;
    int c0 = (t % ctiles) * 32, r0 = (t / ctiles) * 32;
    int tx = tid & 31, ty = tid >> 5;
#pragma unroll
    for (int s = 0; s < 4; ++s) {
      int rr = ty * 4 + s;
      tile[rr][tx] = __float2bfloat16(ip[(size_t)(r0 + rr) * C + c0 + tx]);
    }
    __syncthreads();
#pragma unroll
    for (int s = 0; s < 4; ++s) {
      int cc = ty * 4 + s;
      op[(size_t)(c0 + cc) * R + r0 + tx] = tile[tx][cc];
    }
  } else {
    int unit = (bx - 40224) * 4 + (tid >> 6);  // 384 units = 64 b x 6 cls
    int lane = tid & 63;
    int b = unit & 63, i = unit >> 6;
    const float* tok = x + (size_t)(b * TT + i) * DD;
    const float* g = GW + (size_t)i * DD * 2;
    float p0 = 0.f, p1 = 0.f;
    for (int k = lane; k < DD; k += 64) {
      float tv = tok[k];
      p0 += tv * g[k * 2 + 0];
      p1 += tv * g[k * 2 + 1];
    }
#pragma unroll
    for (int o = 32; o; o >>= 1) { p0 += __shfl_xor(p0, o); p1 += __shfl_xor(p1, o); }
    if (lane == 0) sel[i * 64 + b] = (p0 > p1) ? 0 : ((p1 > p0) ? 1 : 2);
  }
}

// =================== helpers: statically-named LDS buffers keep AA precise ===================
// fragment reads: base = row*128 + ((q^(r&7))<<4), XOR (ks<<6) flips the K-slot bit.
__device__ __forceinline__ void rd_a4(bf16x8 (&af)[4], const char (&arr)[16384], int base) {
#pragma unroll
  for (int ii = 0; ii < 4; ++ii)
    af[ii] = *(const bf16x8*)(&arr[base + ii * 2048]);
}
__device__ __forceinline__ void rd_b4(bf16x8 (&bf)[4], const char (&L)[16384],
                                      const char (&H)[16384], int base) {
#pragma unroll
  for (int j = 0; j < 2; ++j) {
    bf[j]     = *(const bf16x8*)(&L[base + j * 2048]);
    bf[2 + j] = *(const bf16x8*)(&H[base + j * 2048]);
  }
}
// stage one 128-row half-tile (2 x 64-row slabs) into a named 16 KiB array
__device__ __forceinline__ void st2(const char* g, size_t rs, char (&arr)[16384], int ldsb) {
  load_lds16(g,      &arr[ldsb]);
  load_lds16(g + rs, &arr[8192 + ldsb]);
}

template <int MH>
__device__ __forceinline__ void mma16(f32x4 (&acc)[8][4], const bf16x8 (&af)[4], const bf16x8 (&bf)[4]) {
  __builtin_amdgcn_s_setprio(1);   // T5: pays off under phase role-split
#pragma unroll
  for (int ii = 0; ii < 4; ++ii)
#pragma unroll
    for (int j = 0; j < 4; ++j)
      acc[MH * 4 + ii][j] =
          __builtin_amdgcn_mfma_f32_16x16x32_bf16(bf[j], af[ii], acc[MH * 4 + ii][j], 0, 0, 0);
  __builtin_amdgcn_s_setprio(0);
}

// =================== big GEMM: 256x256 tile, BK=64, 8 waves (2Mx4N), static dbuf ===================
// 8 phases / 2 K-tiles (te=2i from *s0, to=2i+1 from *s1). Per phase:
//   {ds_read frags | stage ONE half-tile (2 DMA) | BAR | 16 MFMA | [counted VMCNT] | BAR}
// Stage order: E1:B1(to) E2:A1(to) E3:A0(te+2) E4:B0(te+2) O1:B1(te+2) O2:A1(te+2) O3:A0(to+2) O4:B0(to+2)
// Waits: vmcnt(8)@E2, vmcnt(6)@E4, vmcnt(8)@O2, vmcnt(6)@O4 -> every half has 3-5 phases of slack.
// MODE 0: xb @ W1t, +b1, gelu -> bf16 hid.  MODE 1: hid @ W2t, +b2 -> f32 out (row remap).
template <int MODE>
__device__ __forceinline__
void gemm_big(int bx,
              char (&A0s0)[16384], char (&A1s0)[16384], char (&B0s0)[16384], char (&B1s0)[16384],
              char (&A0s1)[16384], char (&A1s1)[16384], char (&B0s1)[16384], char (&B1s1)[16384],
              const __hip_bfloat16* __restrict__ A, const __hip_bfloat16* __restrict__ Bw,
              const float* __restrict__ bias, void* __restrict__ Out) {
  constexpr int KDIM = (MODE == 0) ? DD : HH;
  constexpr int KT = KDIM / 64;
  constexpr int ITER = KT / 2;           // 6 (MODE0) / 24 (MODE1), both >= 2
  constexpr size_t KB = (size_t)KDIM * 2;
  constexpr size_t R64 = 64 * KB, R128 = 128 * KB;

  const int tid = threadIdx.x;
  const int lane = tid & 63;
  const int q = lane >> 4, r = lane & 15;
  const int wave = tid >> 6;
  const int wave_m = wave >> 2, wave_n = wave & 3;

  int m0, n0;
  if constexpr (MODE == 0) {
    int chunk = bx / 192, local = bx % 192;   // 16 m-blocks share each B panel
    m0 = (chunk * 16 + local % 16) * 256;
    n0 = (local / 16) * 256;
  } else {
    m0 = (bx % 64) * 256;
    n0 = (bx / 64) * 256;
  }

  const int trow = tid >> 3;
  const int sw = ((tid & 7) ^ (trow & 7)) << 4;
  size_t a_row;
  if constexpr (MODE == 0) a_row = (size_t)((m0 >> 8) * TT + 6 + trow);  // m0 % 256 == 0
  else                     a_row = (size_t)(m0 + trow);
  const char* gA = (const char*)A + a_row * KB + sw;
  const char* gB = (const char*)Bw + (size_t)(n0 + trow) * KB + sw;
  const int ldsb = (tid & ~63) * 16;  // wave-uniform LDS base; HW adds lane*16

  const int a_rd0 = (wave_m * 64 + r) * 128 + ((q ^ (r & 7)) << 4);
  const int b_rd0 = (wave_n * 32 + r) * 128 + ((q ^ (r & 7)) << 4);

  f32x4 acc[8][4];
#pragma unroll
  for (int i = 0; i < 8; ++i)
#pragma unroll
    for (int j = 0; j < 4; ++j) acc[i][j] = (f32x4){0.f, 0.f, 0.f, 0.f};
  bf16x8 af[4], bf0[4], bf1[4];

  // prologue: tile0 fully + tile1 A0,B0. FIFO: A0(0) B0(0) B1(0) A1(0) A0(1) B0(1)
  st2(gA,          R64, A0s0, ldsb);
  st2(gB,          R64, B0s0, ldsb);
  st2(gB + R128,   R64, B1s0, ldsb);
  st2(gA + R128,   R64, A1s0, ldsb);
  st2(gA + 128,    R64, A0s1, ldsb);
  st2(gB + 128,    R64, B0s1, ldsb);
  VMCNT(6);   // A0(0),B0(0),B1(0) resident
  BAR();

  for (int i = 0; i < ITER - 1; ++i) {
    // E1
    rd_a4(af, A0s0, a_rd0);
    rd_b4(bf0, B0s0, B1s0, b_rd0);
    st2(gB + R128 + 128, R64, B1s1, ldsb);       // B1(to)
    BAR(); mma16<0>(acc, af, bf0); BAR();
    // E2
    rd_a4(af, A0s0, a_rd0 ^ 64);
    rd_b4(bf1, B0s0, B1s0, b_rd0 ^ 64);
    st2(gA + R128 + 128, R64, A1s1, ldsb);       // A1(to)
    BAR(); mma16<0>(acc, af, bf1); VMCNT(8); BAR();   // A1(te) resident
    // E3
    rd_a4(af, A1s0, a_rd0);
    st2(gA + 256, R64, A0s0, ldsb);              // A0(te+2)
    BAR(); mma16<1>(acc, af, bf0); BAR();
    // E4
    rd_a4(af, A1s0, a_rd0 ^ 64);
    st2(gB + 256, R64, B0s0, ldsb);              // B0(te+2)
    BAR(); mma16<1>(acc, af, bf1); VMCNT(6); BAR();   // A0,B0,B1(to) resident
    // O1
    rd_a4(af, A0s1, a_rd0);
    rd_b4(bf0, B0s1, B1s1, b_rd0);
    st2(gB + R128 + 256, R64, B1s0, ldsb);       // B1(te+2)
    BAR(); mma16<0>(acc, af, bf0); BAR();
    // O2
    rd_a4(af, A0s1, a_rd0 ^ 64);
    rd_b4(bf1, B0s1, B1s1, b_rd0 ^ 64);
    st2(gA + R128 + 256, R64, A1s0, ldsb);       // A1(te+2)
    BAR(); mma16<0>(acc, af, bf1); VMCNT(8); BAR();   // A1(to) resident
    // O3
    rd_a4(af, A1s1, a_rd0);
    st2(gA + 384, R64, A0s1, ldsb);              // A0(to+2)
    BAR(); mma16<1>(acc, af, bf0); BAR();
    // O4
    rd_a4(af, A1s1, a_rd0 ^ 64);
    st2(gB + 384, R64, B0s1, ldsb);              // B0(to+2)
    BAR(); mma16<1>(acc, af, bf1); VMCNT(6); BAR();   // A0,B0,B1(te+2) resident
    gA += 256; gB += 256;
  }

  // peeled final iteration (te=KT-2, to=KT-1): stage only B1(to),A1(to); drain tail
  rd_a4(af, A0s0, a_rd0);
  rd_b4(bf0, B0s0, B1s0, b_rd0);
  st2(gB + R128 + 128, R64, B1s1, ldsb);
  BAR(); mma16<0>(acc, af, bf0); BAR();
  rd_a4(af, A0s0, a_rd0 ^ 64);
  rd_b4(bf1, B0s0, B1s0, b_rd0 ^ 64);
  st2(gA + R128 + 128, R64, A1s1, ldsb);
  BAR(); mma16<0>(acc, af, bf1); VMCNT(8); BAR();
  rd_a4(af, A1s0, a_rd0);
  BAR(); mma16<1>(acc, af, bf0); BAR();
  rd_a4(af, A1s0, a_rd0 ^ 64);
  BAR(); mma16<1>(acc, af, bf1); VMCNT(2); BAR();
  rd_a4(af, A0s1, a_rd0);
  rd_b4(bf0, B0s1, B1s1, b_rd0);
  BAR(); mma16<0>(acc, af, bf0); BAR();
  rd_a4(af, A0s1, a_rd0 ^ 64);
  rd_b4(bf1, B0s1, B1s1, b_rd0 ^ 64);
  BAR(); mma16<0>(acc, af, bf1); VMCNT(0); BAR();
  rd_a4(af, A1s1, a_rd0);
  BAR(); mma16<1>(acc, af, bf0); BAR();
  rd_a4(af, A1s1, a_rd0 ^ 64);
  BAR(); mma16<1>(acc, af, bf1);

  // epilogue: m = m0 + (i>>2)*128 + wave_m*64 + (i&3)*16 + r ; n = n0 + (j>>1)*128 + wave_n*32 + (j&1)*16 + q*4
#pragma unroll
  for (int i = 0; i < 8; ++i) {
    const int m_g = m0 + (i >> 2) * 128 + wave_m * 64 + (i & 3) * 16 + r;
#pragma unroll
    for (int j = 0; j < 4; ++j) {
      const int n_g = n0 + (j >> 1) * 128 + wave_n * 32 + (j & 1) * 16 + q * 4;
      f32x4 v = acc[i][j];
      v += *(const f32x4*)(bias + n_g);
      if constexpr (MODE == 0) {
        union { u16 s[4]; uint2 d; } pk;
#pragma unroll
        for (int rg = 0; rg < 4; ++rg) pk.s[rg] = f2bf(gelu_f(v[rg]));
        *(uint2*)((u16*)Out + (size_t)m_g * HH + n_g) = pk.d;
      } else {
        const int b = m_g >> 8, p = m_g & 255;
        *(f32x4*)((float*)Out + (size_t)(b * TT + 6 + p) * DD + n_g) = v;
      }
    }
  }
}

// =================== cls GEMM: 64x128 tile, BK=64, 8 waves (2Mx4N -> 32x32/wave) ===================
// reuses three of the big-GEMM arrays (different blocks). __syncthreads drains everything -> safe.
template <int MODE>
__device__ __forceinline__
void gemm_cls(int bx, char (&Asp)[16384], char (&BsL)[16384], char (&BsH)[16384],
              const __hip_bfloat16* __restrict__ A, const __hip_bfloat16* __restrict__ Bw,
              const float* __restrict__ bias, void* __restrict__ Out, const int* __restrict__ sel) {
  constexpr int KDIM = (MODE == 2) ? DD : HH;
  constexpr int KT = KDIM / 64;

  const int tid = threadIdx.x;
  const int lane = tid & 63;
  const int q = lane >> 4, r = lane & 15;
  const int wave = tid >> 6;
  const int wave_m = wave >> 2, wave_n = wave & 3;

  int n0, combo, e;
  if constexpr (MODE == 2) { n0 = (bx % 24) * 128; combo = bx / 24; e = A_FIRST[combo]; }
  else                     { n0 = (bx % 6) * 128;  combo = bx / 6;  e = A_SECOND[combo]; }
  const int cls_i = combo >> 1;
  const __hip_bfloat16* Bp = Bw + (size_t)e * DD * HH;
  const float* biasp = bias + e * ((MODE == 2) ? HH : DD);

  const int trow = tid >> 3;   // 0..63
  const int sw = ((tid & 7) ^ (trow & 7)) << 4;
  const char* gA = (const char*)A +
      ((MODE == 2) ? (size_t)(trow * TT + cls_i) * (DD * 2)
                   : (size_t)(combo * 64 + trow) * (HH * 2)) + sw;
  const char* gB = (const char*)Bp + (size_t)(n0 + trow) * (KDIM * 2) + sw;
  const int ldsb = (tid & ~63) * 16;
  const int sa = (q ^ (r & 7)) << 4;

  f32x4 acc[2][2];
  acc[0][0] = acc[0][1] = acc[1][0] = acc[1][1] = (f32x4){0.f, 0.f, 0.f, 0.f};

  const char* bb = (wave_n < 2) ? &BsL[0] : &BsH[0];
  const int brow = (wave_n & 1) * 32;

  for (int t = 0; t < KT; ++t) {
    load_lds16(gA + t * 128, &Asp[ldsb]);
    load_lds16(gB + t * 128, &BsL[ldsb]);
    load_lds16(gB + (size_t)64 * (KDIM * 2) + t * 128, &BsH[ldsb]);
    __syncthreads();
#pragma unroll
    for (int ks = 0; ks < 2; ++ks) {
      bf16x8 a0 = *(const bf16x8*)(&Asp[(wave_m * 32 + r) * 128 + (sa ^ (ks << 6))]);
      bf16x8 a1 = *(const bf16x8*)(&Asp[(wave_m * 32 + 16 + r) * 128 + (sa ^ (ks << 6))]);
      bf16x8 b0 = *(const bf16x8*)(bb + (brow + r) * 128 + (sa ^ (ks << 6)));
      bf16x8 b1 = *(const bf16x8*)(bb + (brow + 16 + r) * 128 + (sa ^ (ks << 6)));
      acc[0][0] = __builtin_amdgcn_mfma_f32_16x16x32_bf16(b0, a0, acc[0][0], 0, 0, 0);
      acc[0][1] = __builtin_amdgcn_mfma_f32_16x16x32_bf16(b1, a0, acc[0][1], 0, 0, 0);
      acc[1][0] = __builtin_amdgcn_mfma_f32_16x16x32_bf16(b0, a1, acc[1][0], 0, 0, 0);
      acc[1][1] = __builtin_amdgcn_mfma_f32_16x16x32_bf16(b1, a1, acc[1][1], 0, 0, 0);
    }
    __syncthreads();
  }

#pragma unroll
  for (int i = 0; i < 2; ++i) {
    const int m_g = wave_m * 32 + i * 16 + r;   // batch index 0..63
#pragma unroll
    for (int j = 0; j < 2; ++j) {
      const int n_g = n0 + wave_n * 32 + j * 16 + q * 4;
      f32x4 v = acc[i][j];
      v += *(const f32x4*)(biasp + n_g);
      if constexpr (MODE == 2) {
        union { u16 s[4]; uint2 d; } pk;
#pragma unroll
        for (int rg = 0; rg < 4; ++rg) pk.s[rg] = f2bf(gelu_f(v[rg]));
        *(uint2*)((u16*)Out + (size_t)(combo * 64 + m_g) * HH + n_g) = pk.d;
      } else {
        const int s = sel[cls_i * 64 + m_g];
        const int jj = combo & 1;
        float* dst = (float*)Out + (size_t)(m_g * TT + cls_i) * DD + n_g;
        if (s == jj)                    *(f32x4*)dst = v;
        else if (jj == 0 && s == 2)     *(f32x4*)dst = (f32x4){0.f, 0.f, 0.f, 0.f};
      }
    }
  }
}

// mega1: blocks [0,768) patch L1 (256x256, 8-phase); [768,1056) cls L1 (64x128)
__global__ __launch_bounds__(512, 2)
void mega1(const __hip_bfloat16* __restrict__ xb, const __hip_bfloat16* __restrict__ W1t,
           const float* __restrict__ b1, __hip_bfloat16* __restrict__ hid,
           const __hip_bfloat16* __restrict__ A1t, const float* __restrict__ A1b,
           __hip_bfloat16* __restrict__ hcls) {
  __shared__ __align__(16) char A0s0[16384], A1s0[16384], B0s0[16384], B1s0[16384],
                                A0s1[16384], A1s1[16384], B0s1[16384], B1s1[16384];
  int bx = blockIdx.x;
  if (bx < 768) gemm_big<0>(bx, A0s0, A1s0, B0s0, B1s0, A0s1, A1s1, B0s1, B1s1, xb, W1t, b1, hid);
  else          gemm_cls<2>(bx - 768, A0s0, B0s0, B1s0, xb, A1t, A1b, hcls, nullptr);
}

// mega2: blocks [0,192) patch L2 (256x256, 8-phase); [192,264) cls L2 (64x128, masked)
__global__ __launch_bounds__(512, 2)
void mega2(const __hip_bfloat16* __restrict__ hid, const __hip_bfloat16* __restrict__ W2t,
           const float* __restrict__ b2, float* __restrict__ out,
           const __hip_bfloat16* __restrict__ hcls, const __hip_bfloat16* __restrict__ A2t,
           const float* __restrict__ A2b, const int* __restrict__ sel) {
  __shared__ __align__(16) char A0s0[16384], A1s0[16384], B0s0[16384], B1s0[16384],
                                A0s1[16384], A1s1[16384], B0s1[16384], B1s1[16384];
  int bx = blockIdx.x;
  if (bx < 192) gemm_big<1>(bx, A0s0, A1s0, B0s0, B1s0, A0s1, A1s1, B0s1, B1s1, hid, W2t, b2, out);
  else          gemm_cls<3>(bx - 192, A0s0, B0s0, B1s0, hcls, A2t, A2b, out, sel);
}

extern "C" void kernel_launch(void* const* d_in, const int* in_sizes, int n_in,
                              void* d_out, int out_size, void* d_ws, size_t ws_size,
                              hipStream_t stream) {
  const float* x   = (const float*)d_in[0];
  const float* W1  = (const float*)d_in[1];
  const float* b1  = (const float*)d_in[2];
  const float* W2  = (const float*)d_in[3];
  const float* b2  = (const float*)d_in[4];
  const float* A1W = (const float*)d_in[5];
  const float* A1b = (const float*)d_in[6];
  const float* A2W = (const float*)d_in[7];
  const float* A2b = (const float*)d_in[8];
  const float* GW  = (const float*)d_in[9];
  float* out = (float*)d_out;

  char* ws = (char*)d_ws;
  __hip_bfloat16* xb   = (__hip_bfloat16*)(ws + 0);          // 25,755,648
  __hip_bfloat16* W1t  = (__hip_bfloat16*)(ws + 25755648);   //  4,718,592
  __hip_bfloat16* W2t  = (__hip_bfloat16*)(ws + 30474240);   //  4,718,592
  __hip_bfloat16* A1t  = (__hip_bfloat16*)(ws + 35192832);   // 23,592,960
  __hip_bfloat16* A2t  = (__hip_bfloat16*)(ws + 58785792);   // 23,592,960
  __hip_bfloat16* hcls = (__hip_bfloat16*)(ws + 82378752);   //  4,718,592
  int* sel             = (int*)(ws + 87097344);
  __hip_bfloat16* hid  = (__hip_bfloat16*)(ws + 87099136);   // 100,663,296

  preproc<<<40320, 256, 0, stream>>>(x, W1, A1W, W2, A2W, GW, xb, W1t, A1t, W2t, A2t, sel);
  mega1<<<1056, 512, 0, stream>>>(xb, W1t, b1, hid, A1t, A1b, hcls);
  mega2<<<264, 512, 0, stream>>>(hid, W2t, b2, out, hcls, A2t, A2b, sel);
}

// Round 3
// 387.232 us; speedup vs baseline: 1.0831x; 1.0831x over previous
//
#include <hip/hip_runtime.h>
#include <hip/hip_bf16.h>

#define DD 768
#define HH 3072
#define BB 64
#define TT 262   // NCLS + P tokens per batch

typedef __bf16 bf16x8 __attribute__((ext_vector_type(8)));
typedef float f32x4 __attribute__((ext_vector_type(4)));
typedef unsigned short u16;
typedef unsigned int u32;

__device__ __constant__ int A_FIRST[12]  = {0,3, 0,4, 1,3, 1,4, 2,3, 2,4};
__device__ __constant__ int A_SECOND[12] = {3,0, 4,0, 3,1, 4,1, 3,2, 4,2};

// tanh-form gelu: max |dev| from exact erf-gelu ~0.003 abs; output tol 0.039 -> safe
__device__ __forceinline__ float gelu_f(float x) {
  float n2t = x * fmaf(x * x, -0.0713548163f, -1.5957691216f);
  return x * __builtin_amdgcn_rcpf(1.0f + __expf(n2t));
}

__device__ __forceinline__ u16 f2bf(float x) {
  u32 u = __builtin_bit_cast(u32, x);
  return (u16)((u + 0x7fffu + ((u >> 16) & 1u)) >> 16);  // RNE
}

__device__ __forceinline__ void load_lds16(const void* g, void* l) {
  __builtin_amdgcn_global_load_lds(
      (const __attribute__((address_space(1))) void*)g,
      (__attribute__((address_space(3))) void*)l,
      16, 0, 0);
}

// counted waits / raw barrier (T4): raw s_barrier does NOT drain vmcnt.
#define VMCNT(n) asm volatile("s_waitcnt vmcnt(" #n ")")
#define BAR() __builtin_amdgcn_s_barrier()
// rule #18: lgkmcnt on asm ds_read results needs a sched_barrier fence so MFMA can't hoist past it
#define WAIT_FRAGS() do { asm volatile("s_waitcnt lgkmcnt(0)"); __builtin_amdgcn_sched_barrier(0); } while (0)

// inline-asm LDS read: opaque to SIInsertWaitcnts -> no compiler-inserted vmcnt drains
// (the pass conservatively drains before compiler-visible ds_reads that may alias LDS-DMA).
template <int IMM>
__device__ __forceinline__ bf16x8 dsr(u32 addr) {
  f32x4 o;
  asm volatile("ds_read_b128 %0, %1 offset:%c2" : "=v"(o) : "v"(addr), "i"(IMM));
  return __builtin_bit_cast(bf16x8, o);
}

// =================== fused preprocessing: cast_x | transpose x2 | gate ===================
__global__ __launch_bounds__(256)
void preproc(const float* __restrict__ x,
             const float* __restrict__ W1, const float* __restrict__ A1W,
             const float* __restrict__ W2, const float* __restrict__ A2W,
             const float* __restrict__ GW,
             __hip_bfloat16* __restrict__ xb,
             __hip_bfloat16* __restrict__ W1t, __hip_bfloat16* __restrict__ A1t,
             __hip_bfloat16* __restrict__ W2t, __hip_bfloat16* __restrict__ A2t,
             int* __restrict__ sel) {
  __shared__ __hip_bfloat16 tile[32][33];
  const int bx = blockIdx.x;
  const int tid = threadIdx.x;
  if (bx < 12576) {
    int i = bx * 256 + tid;  // 12576*256 == 3219456 exactly
    float4 v = ((const float4*)x)[i];
    union { u16 s[4]; uint2 d; } pk;
    pk.s[0] = f2bf(v.x); pk.s[1] = f2bf(v.y); pk.s[2] = f2bf(v.z); pk.s[3] = f2bf(v.w);
    *(uint2*)((u16*)xb + (size_t)i * 4) = pk.d;
  } else if (bx < 40224) {
    int R, C;
    const float* ip;
    __hip_bfloat16* op;
    int t;
    if (bx < 26400) {
      t = bx - 12576; R = DD; C = HH;
      int z = t / 2304; t %= 2304;
      ip = z ? (A1W + (size_t)(z - 1) * DD * HH) : W1;
      op = z ? (A1t + (size_t)(z - 1) * DD * HH) : W1t;
    } else {
      t = bx - 26400; R = HH; C = DD;
      int z = t / 2304; t %= 2304;
      ip = z ? (A2W + (size_t)(z - 1) * DD * HH) : W2;
      op = z ? (A2t + (size_t)(z - 1) * DD * HH) : W2t;
    }
    int ctiles = C >> 5;
    int c0 = (t % ctiles) * 32, r0 = (t / ctiles) * 32;
    int tx = tid & 31, ty = tid >> 5;
#pragma unroll
    for (int s = 0; s < 4; ++s) {
      int rr = ty * 4 + s;
      tile[rr][tx] = __float2bfloat16(ip[(size_t)(r0 + rr) * C + c0 + tx]);
    }
    __syncthreads();
#pragma unroll
    for (int s = 0; s < 4; ++s) {
      int cc = ty * 4 + s;
      op[(size_t)(c0 + cc) * R + r0 + tx] = tile[tx][cc];
    }
  } else {
    int unit = (bx - 40224) * 4 + (tid >> 6);  // 384 units = 64 b x 6 cls
    int lane = tid & 63;
    int b = unit & 63, i = unit >> 6;
    const float* tok = x + (size_t)(b * TT + i) * DD;
    const float* g = GW + (size_t)i * DD * 2;
    float p0 = 0.f, p1 = 0.f;
    for (int k = lane; k < DD; k += 64) {
      float tv = tok[k];
      p0 += tv * g[k * 2 + 0];
      p1 += tv * g[k * 2 + 1];
    }
#pragma unroll
    for (int o = 32; o; o >>= 1) { p0 += __shfl_xor(p0, o); p1 += __shfl_xor(p1, o); }
    if (lane == 0) sel[i * 64 + b] = (p0 > p1) ? 0 : ((p1 > p0) ? 1 : 2);
  }
}

// =================== asm fragment readers (offsets are compile-time immediates) ===================
// A region layout in smem: A0s0@0  A1s0@16K  A0s1@32K  A1s1@48K   (each 16K = 128 rows x 128B)
// B region layout:         base 64K + {B0s0@0, B1s0@16K, B0s1@32K, B1s1@48K}
template <int R>
__device__ __forceinline__ void rdA4(bf16x8 (&af)[4], u32 a) {
  af[0] = dsr<R + 0>(a);    af[1] = dsr<R + 2048>(a);
  af[2] = dsr<R + 4096>(a); af[3] = dsr<R + 6144>(a);
}
template <int R>
__device__ __forceinline__ void rdB4(bf16x8 (&bf)[4], u32 b) {
  bf[0] = dsr<R + 0>(b);     bf[1] = dsr<R + 2048>(b);
  bf[2] = dsr<R + 16384>(b); bf[3] = dsr<R + 18432>(b);
}

__device__ __forceinline__ void st2r(const char* g, size_t r64, char* smem, int region, int ldsb) {
  load_lds16(g,       smem + region + ldsb);
  load_lds16(g + r64, smem + region + 8192 + ldsb);
}

template <int MH>
__device__ __forceinline__ void mma16(f32x4 (&acc)[8][4], const bf16x8 (&af)[4], const bf16x8 (&bf)[4]) {
  __builtin_amdgcn_s_setprio(1);   // T5: pays off under phase role-split
#pragma unroll
  for (int ii = 0; ii < 4; ++ii)
#pragma unroll
    for (int j = 0; j < 4; ++j)
      acc[MH * 4 + ii][j] =
          __builtin_amdgcn_mfma_f32_16x16x32_bf16(bf[j], af[ii], acc[MH * 4 + ii][j], 0, 0, 0);
  __builtin_amdgcn_s_setprio(0);
}

// =================== big GEMM: 256x256 tile, BK=64, 8 waves (2Mx4N), dbuf, asm reads ===================
// 8 phases / 2 K-tiles (te=2i, to=2i+1). Per phase:
//   {asm ds_read frags | stage ONE half-tile (2 DMA) | BAR | lgkmcnt(0)+sched_barrier | 16 MFMA | [VMCNT] | BAR}
// Stage order: E1:B1(to) E2:A1(to) E3:A0(te+2) E4:B0(te+2) O1:B1(te+2) O2:A1(te+2) O3:A0(to+2) O4:B0(to+2)
// Waits: vmcnt(8)@E2/O2, vmcnt(6)@E4/O4 (FIFO-verified; every half-tile has 3-5 phases of slack, never 0).
// MODE 0: xb @ W1t, +b1, gelu -> bf16 hid.  MODE 1: hid @ W2t, +b2 -> f32 out (row remap).
template <int MODE>
__device__ __forceinline__
void gemm_big(char* __restrict__ smem, int bx,
              const __hip_bfloat16* __restrict__ A, const __hip_bfloat16* __restrict__ Bw,
              const float* __restrict__ bias, void* __restrict__ Out) {
  constexpr int KDIM = (MODE == 0) ? DD : HH;
  constexpr int KT = KDIM / 64;
  constexpr int ITER = KT / 2;           // 6 (MODE0) / 24 (MODE1)
  constexpr size_t KB = (size_t)KDIM * 2;
  constexpr size_t R64 = 64 * KB, R128 = 128 * KB;
  constexpr int A0S0 = 0, A1S0 = 16384, A0S1 = 32768, A1S1 = 49152;
  constexpr int BB0S0 = 65536, BB1S0 = 81920, BB0S1 = 98304, BB1S1 = 114688;

  const int tid = threadIdx.x;
  const int lane = tid & 63;
  const int q = lane >> 4, r = lane & 15;
  const int wave = tid >> 6;
  const int wave_m = wave >> 2, wave_n = wave & 3;

  int m0, n0;
  if constexpr (MODE == 0) {
    int chunk = bx / 192, local = bx % 192;   // 16 m-blocks share each B panel
    m0 = (chunk * 16 + local % 16) * 256;
    n0 = (local / 16) * 256;
  } else {
    m0 = (bx % 64) * 256;
    n0 = (bx / 64) * 256;
  }

  const int trow = tid >> 3;
  const int sw = ((tid & 7) ^ (trow & 7)) << 4;
  size_t a_row;
  if constexpr (MODE == 0) a_row = (size_t)((m0 >> 8) * TT + 6 + trow);  // m0 % 256 == 0
  else                     a_row = (size_t)(m0 + trow);
  const char* gA = (const char*)A + a_row * KB + sw;
  const char* gB = (const char*)Bw + (size_t)(n0 + trow) * KB + sw;
  const int ldsb = (tid & ~63) * 16;  // wave-uniform LDS base; HW adds lane*16

  // persistent LDS read addresses (low 32 bits of generic pointer = LDS offset)
  const u32 lds0 = (u32)(uintptr_t)smem;
  const u32 aA0 = lds0 + (wave_m * 64 + r) * 128 + ((q ^ (r & 7)) << 4);
  const u32 aA1 = aA0 ^ 64;                 // ks=1 (XOR folds into the slot swizzle)
  const u32 aB0 = lds0 + 65536 + (wave_n * 32 + r) * 128 + ((q ^ (r & 7)) << 4);
  const u32 aB1 = aB0 ^ 64;

  f32x4 acc[8][4];
#pragma unroll
  for (int i = 0; i < 8; ++i)
#pragma unroll
    for (int j = 0; j < 4; ++j) acc[i][j] = (f32x4){0.f, 0.f, 0.f, 0.f};
  bf16x8 af[4], bf0[4], bf1[4];

  // prologue: tile0 fully + tile1 A0,B0. FIFO: A0(0) B0(0) B1(0) A1(0) A0(1) B0(1)
  st2r(gA,        R64, smem, A0S0,  ldsb);
  st2r(gB,        R64, smem, BB0S0, ldsb);
  st2r(gB + R128, R64, smem, BB1S0, ldsb);
  st2r(gA + R128, R64, smem, A1S0,  ldsb);
  st2r(gA + 128,  R64, smem, A0S1,  ldsb);
  st2r(gB + 128,  R64, smem, BB0S1, ldsb);
  VMCNT(6);   // A0(0),B0(0),B1(0) resident
  BAR();

#pragma unroll 1
  for (int i = 0; i < ITER - 1; ++i) {
    // E1
    rdA4<A0S0>(af, aA0);
    rdB4<0>(bf0, aB0);
    st2r(gB + R128 + 128, R64, smem, BB1S1, ldsb);   // B1(to)
    BAR(); WAIT_FRAGS(); mma16<0>(acc, af, bf0); BAR();
    // E2
    rdA4<A0S0>(af, aA1);
    rdB4<0>(bf1, aB1);
    st2r(gA + R128 + 128, R64, smem, A1S1, ldsb);    // A1(to)
    BAR(); WAIT_FRAGS(); mma16<0>(acc, af, bf1); VMCNT(8); BAR();   // A1(te) resident
    // E3
    rdA4<A1S0>(af, aA0);
    st2r(gA + 256, R64, smem, A0S0, ldsb);           // A0(te+2)
    BAR(); WAIT_FRAGS(); mma16<1>(acc, af, bf0); BAR();
    // E4
    rdA4<A1S0>(af, aA1);
    st2r(gB + 256, R64, smem, BB0S0, ldsb);          // B0(te+2)
    BAR(); WAIT_FRAGS(); mma16<1>(acc, af, bf1); VMCNT(6); BAR();   // A0,B0,B1(to) resident
    // O1
    rdA4<A0S1>(af, aA0);
    rdB4<32768>(bf0, aB0);
    st2r(gB + R128 + 256, R64, smem, BB1S0, ldsb);   // B1(te+2)
    BAR(); WAIT_FRAGS(); mma16<0>(acc, af, bf0); BAR();
    // O2
    rdA4<A0S1>(af, aA1);
    rdB4<32768>(bf1, aB1);
    st2r(gA + R128 + 256, R64, smem, A1S0, ldsb);    // A1(te+2)
    BAR(); WAIT_FRAGS(); mma16<0>(acc, af, bf1); VMCNT(8); BAR();   // A1(to) resident
    // O3
    rdA4<A1S1>(af, aA0);
    st2r(gA + 384, R64, smem, A0S1, ldsb);           // A0(to+2)
    BAR(); WAIT_FRAGS(); mma16<1>(acc, af, bf0); BAR();
    // O4
    rdA4<A1S1>(af, aA1);
    st2r(gB + 384, R64, smem, BB0S1, ldsb);          // B0(to+2)
    BAR(); WAIT_FRAGS(); mma16<1>(acc, af, bf1); VMCNT(6); BAR();   // A0,B0,B1(te+2) resident
    gA += 256; gB += 256;
  }

  // peeled final iteration (te=KT-2, to=KT-1): stage only B1(to),A1(to); drain tail
  rdA4<A0S0>(af, aA0);
  rdB4<0>(bf0, aB0);
  st2r(gB + R128 + 128, R64, smem, BB1S1, ldsb);
  BAR(); WAIT_FRAGS(); mma16<0>(acc, af, bf0); BAR();
  rdA4<A0S0>(af, aA1);
  rdB4<0>(bf1, aB1);
  st2r(gA + R128 + 128, R64, smem, A1S1, ldsb);
  BAR(); WAIT_FRAGS(); mma16<0>(acc, af, bf1); VMCNT(8); BAR();
  rdA4<A1S0>(af, aA0);
  BAR(); WAIT_FRAGS(); mma16<1>(acc, af, bf0); BAR();
  rdA4<A1S0>(af, aA1);
  BAR(); WAIT_FRAGS(); mma16<1>(acc, af, bf1); VMCNT(2); BAR();
  rdA4<A0S1>(af, aA0);
  rdB4<32768>(bf0, aB0);
  BAR(); WAIT_FRAGS(); mma16<0>(acc, af, bf0); BAR();
  rdA4<A0S1>(af, aA1);
  rdB4<32768>(bf1, aB1);
  BAR(); WAIT_FRAGS(); mma16<0>(acc, af, bf1); VMCNT(0); BAR();
  rdA4<A1S1>(af, aA0);
  BAR(); WAIT_FRAGS(); mma16<1>(acc, af, bf0); BAR();
  rdA4<A1S1>(af, aA1);
  BAR(); WAIT_FRAGS(); mma16<1>(acc, af, bf1);

  // epilogue: m = m0 + (i>>2)*128 + wave_m*64 + (i&3)*16 + r ; n = n0 + (j>>1)*128 + wave_n*32 + (j&1)*16 + q*4
#pragma unroll
  for (int i = 0; i < 8; ++i) {
    const int m_g = m0 + (i >> 2) * 128 + wave_m * 64 + (i & 3) * 16 + r;
#pragma unroll
    for (int j = 0; j < 4; ++j) {
      const int n_g = n0 + (j >> 1) * 128 + wave_n * 32 + (j & 1) * 16 + q * 4;
      f32x4 v = acc[i][j];
      v += *(const f32x4*)(bias + n_g);
      if constexpr (MODE == 0) {
        union { u16 s[4]; uint2 d; } pk;
#pragma unroll
        for (int rg = 0; rg < 4; ++rg) pk.s[rg] = f2bf(gelu_f(v[rg]));
        *(uint2*)((u16*)Out + (size_t)m_g * HH + n_g) = pk.d;
      } else {
        const int b = m_g >> 8, p = m_g & 255;
        *(f32x4*)((float*)Out + (size_t)(b * TT + 6 + p) * DD + n_g) = v;
      }
    }
  }
}

// =================== cls GEMM: 64x128 tile, BK=64, 8 waves (2Mx4N -> 32x32/wave) ===================
// simple __syncthreads structure (tiny fraction of runtime); As@0 (8K), Bs@8K (16K) of smem.
template <int MODE>
__device__ __forceinline__
void gemm_cls(char* __restrict__ smem, int bx,
              const __hip_bfloat16* __restrict__ A, const __hip_bfloat16* __restrict__ Bw,
              const float* __restrict__ bias, void* __restrict__ Out, const int* __restrict__ sel) {
  constexpr int KDIM = (MODE == 2) ? DD : HH;
  constexpr int KT = KDIM / 64;
  char* As = smem;
  char* Bs = smem + 8192;

  const int tid = threadIdx.x;
  const int lane = tid & 63;
  const int q = lane >> 4, r = lane & 15;
  const int wave = tid >> 6;
  const int wave_m = wave >> 2, wave_n = wave & 3;

  int n0, combo, e;
  if constexpr (MODE == 2) { n0 = (bx % 24) * 128; combo = bx / 24; e = A_FIRST[combo]; }
  else                     { n0 = (bx % 6) * 128;  combo = bx / 6;  e = A_SECOND[combo]; }
  const int cls_i = combo >> 1;
  const __hip_bfloat16* Bp = Bw + (size_t)e * DD * HH;
  const float* biasp = bias + e * ((MODE == 2) ? HH : DD);

  const int trow = tid >> 3;   // 0..63
  const int sw = ((tid & 7) ^ (trow & 7)) << 4;
  const char* gA = (const char*)A +
      ((MODE == 2) ? (size_t)(trow * TT + cls_i) * (DD * 2)
                   : (size_t)(combo * 64 + trow) * (HH * 2)) + sw;
  const char* gB = (const char*)Bp + (size_t)(n0 + trow) * (KDIM * 2) + sw;
  const int ldsb = (tid & ~63) * 16;
  const int sa = (q ^ (r & 7)) << 4;

  f32x4 acc[2][2];
  acc[0][0] = acc[0][1] = acc[1][0] = acc[1][1] = (f32x4){0.f, 0.f, 0.f, 0.f};

  for (int t = 0; t < KT; ++t) {
    load_lds16(gA + t * 128, As + ldsb);
    load_lds16(gB + t * 128, Bs + ldsb);
    load_lds16(gB + (size_t)64 * (KDIM * 2) + t * 128, Bs + 8192 + ldsb);
    __syncthreads();
#pragma unroll
    for (int ks = 0; ks < 2; ++ks) {
      bf16x8 a0 = *(const bf16x8*)(As + (wave_m * 32 + r) * 128 + (sa ^ (ks << 6)));
      bf16x8 a1 = *(const bf16x8*)(As + (wave_m * 32 + 16 + r) * 128 + (sa ^ (ks << 6)));
      bf16x8 b0 = *(const bf16x8*)(Bs + (wave_n * 32 + r) * 128 + (sa ^ (ks << 6)));
      bf16x8 b1 = *(const bf16x8*)(Bs + (wave_n * 32 + 16 + r) * 128 + (sa ^ (ks << 6)));
      acc[0][0] = __builtin_amdgcn_mfma_f32_16x16x32_bf16(b0, a0, acc[0][0], 0, 0, 0);
      acc[0][1] = __builtin_amdgcn_mfma_f32_16x16x32_bf16(b1, a0, acc[0][1], 0, 0, 0);
      acc[1][0] = __builtin_amdgcn_mfma_f32_16x16x32_bf16(b0, a1, acc[1][0], 0, 0, 0);
      acc[1][1] = __builtin_amdgcn_mfma_f32_16x16x32_bf16(b1, a1, acc[1][1], 0, 0, 0);
    }
    __syncthreads();
  }

#pragma unroll
  for (int i = 0; i < 2; ++i) {
    const int m_g = wave_m * 32 + i * 16 + r;   // batch index 0..63
#pragma unroll
    for (int j = 0; j < 2; ++j) {
      const int n_g = n0 + wave_n * 32 + j * 16 + q * 4;
      f32x4 v = acc[i][j];
      v += *(const f32x4*)(biasp + n_g);
      if constexpr (MODE == 2) {
        union { u16 s[4]; uint2 d; } pk;
#pragma unroll
        for (int rg = 0; rg < 4; ++rg) pk.s[rg] = f2bf(gelu_f(v[rg]));
        *(uint2*)((u16*)Out + (size_t)(combo * 64 + m_g) * HH + n_g) = pk.d;
      } else {
        const int s = sel[cls_i * 64 + m_g];
        const int jj = combo & 1;
        float* dst = (float*)Out + (size_t)(m_g * TT + cls_i) * DD + n_g;
        if (s == jj)                    *(f32x4*)dst = v;
        else if (jj == 0 && s == 2)     *(f32x4*)dst = (f32x4){0.f, 0.f, 0.f, 0.f};
      }
    }
  }
}

// mega1: blocks [0,768) patch L1 (256x256, 8-phase); [768,1056) cls L1 (64x128)
__global__ __launch_bounds__(512, 2)
void mega1(const __hip_bfloat16* __restrict__ xb, const __hip_bfloat16* __restrict__ W1t,
           const float* __restrict__ b1, __hip_bfloat16* __restrict__ hid,
           const __hip_bfloat16* __restrict__ A1t, const float* __restrict__ A1b,
           __hip_bfloat16* __restrict__ hcls) {
  __shared__ __align__(16) char smem[131072];
  int bx = blockIdx.x;
  if (bx < 768) gemm_big<0>(smem, bx, xb, W1t, b1, hid);
  else          gemm_cls<2>(smem, bx - 768, xb, A1t, A1b, hcls, nullptr);
}

// mega2: blocks [0,192) patch L2 (256x256, 8-phase); [192,264) cls L2 (64x128, masked)
__global__ __launch_bounds__(512, 2)
void mega2(const __hip_bfloat16* __restrict__ hid, const __hip_bfloat16* __restrict__ W2t,
           const float* __restrict__ b2, float* __restrict__ out,
           const __hip_bfloat16* __restrict__ hcls, const __hip_bfloat16* __restrict__ A2t,
           const float* __restrict__ A2b, const int* __restrict__ sel) {
  __shared__ __align__(16) char smem[131072];
  int bx = blockIdx.x;
  if (bx < 192) gemm_big<1>(smem, bx, hid, W2t, b2, out);
  else          gemm_cls<3>(smem, bx - 192, hcls, A2t, A2b, out, sel);
}

extern "C" void kernel_launch(void* const* d_in, const int* in_sizes, int n_in,
                              void* d_out, int out_size, void* d_ws, size_t ws_size,
                              hipStream_t stream) {
  const float* x   = (const float*)d_in[0];
  const float* W1  = (const float*)d_in[1];
  const float* b1  = (const float*)d_in[2];
  const float* W2  = (const float*)d_in[3];
  const float* b2  = (const float*)d_in[4];
  const float* A1W = (const float*)d_in[5];
  const float* A1b = (const float*)d_in[6];
  const float* A2W = (const float*)d_in[7];
  const float* A2b = (const float*)d_in[8];
  const float* GW  = (const float*)d_in[9];
  float* out = (float*)d_out;

  char* ws = (char*)d_ws;
  __hip_bfloat16* xb   = (__hip_bfloat16*)(ws + 0);          // 25,755,648
  __hip_bfloat16* W1t  = (__hip_bfloat16*)(ws + 25755648);   //  4,718,592
  __hip_bfloat16* W2t  = (__hip_bfloat16*)(ws + 30474240);   //  4,718,592
  __hip_bfloat16* A1t  = (__hip_bfloat16*)(ws + 35192832);   // 23,592,960
  __hip_bfloat16* A2t  = (__hip_bfloat16*)(ws + 58785792);   // 23,592,960
  __hip_bfloat16* hcls = (__hip_bfloat16*)(ws + 82378752);   //  4,718,592
  int* sel             = (int*)(ws + 87097344);
  __hip_bfloat16* hid  = (__hip_bfloat16*)(ws + 87099136);   // 100,663,296

  preproc<<<40320, 256, 0, stream>>>(x, W1, A1W, W2, A2W, GW, xb, W1t, A1t, W2t, A2t, sel);
  mega1<<<1056, 512, 0, stream>>>(xb, W1t, b1, hid, A1t, A1b, hcls);
  mega2<<<264, 512, 0, stream>>>(hid, W2t, b2, out, hcls, A2t, A2b, sel);
}